// Round 10
// baseline (1003.071 us; speedup 1.0000x reference)
//
#include <hip/hip_runtime.h>
#include <stdint.h>

// ===== LinearQ4_0: out[8192,11008] = x[8192,4096] * W^T, W q4_0 packed =====
#define IN_F   4096
#define OUT_F  11008
#define M_ROWS 8192
#define BM 128
#define BN 256
#define BK 64
#define NTILE_K (IN_F / BK)   // 64 K-tiles, 2 per iteration -> 32 iters

typedef __attribute__((ext_vector_type(4))) float  f32x4;
typedef __attribute__((ext_vector_type(4))) int    int4v;
typedef __attribute__((ext_vector_type(8))) unsigned short ushort8;
typedef __bf16 bf16x8 __attribute__((ext_vector_type(8)));

__device__ __forceinline__ unsigned short f2bf(float f) {
  unsigned int u = __builtin_bit_cast(unsigned int, f);
  u += 0x7fffu + ((u >> 16) & 1u);
  return (unsigned short)(u >> 16);
}

// ---- kernel 1: dequantize q4_0 -> bf16 W[OUT_F][IN_F] (nt loads: read-once) ----
__global__ __launch_bounds__(256) void dequant_q40(const int* __restrict__ w,
                                                   const float* __restrict__ sc,
                                                   unsigned short* __restrict__ wb) {
  const int total8 = (OUT_F * IN_F) / 8;
  for (int t = blockIdx.x * blockDim.x + threadIdx.x; t < total8;
       t += gridDim.x * blockDim.x) {
    const int f0  = t * 8;
    const int p   = f0 >> 7;
    const int nib = (f0 >> 6) & 1;
    const int j0  = f0 & 63;
    const float scale = sc[f0 >> 6];
    const int* src = w + p * 64 + j0;
    const int4v b0 = __builtin_nontemporal_load(reinterpret_cast<const int4v*>(src));
    const int4v b1 = __builtin_nontemporal_load(reinterpret_cast<const int4v*>(src + 4));
    ushort8 r;
#pragma unroll
    for (int e = 0; e < 4; ++e) {
      const int v0 = b0[e], v1 = b1[e];
      const int q0 = nib ? ((v0 << 28) >> 28) : (v0 >> 4);
      const int q1 = nib ? ((v1 << 28) >> 28) : (v1 >> 4);
      r[e]     = f2bf((float)q0 * scale);
      r[4 + e] = f2bf((float)q1 * scale);
    }
    *reinterpret_cast<ushort8*>(wb + f0) = r;
  }
}

// ---- kernel 2: x fp32 -> bf16 (nt loads: read-once) ----
__global__ __launch_bounds__(256) void cvt_x(const float* __restrict__ x,
                                             unsigned short* __restrict__ xb) {
  const int total8 = (M_ROWS * IN_F) / 8;
  for (int t = blockIdx.x * blockDim.x + threadIdx.x; t < total8;
       t += gridDim.x * blockDim.x) {
    const f32x4 a0 = __builtin_nontemporal_load(reinterpret_cast<const f32x4*>(x + t * 8));
    const f32x4 a1 = __builtin_nontemporal_load(reinterpret_cast<const f32x4*>(x + t * 8 + 4));
    ushort8 r;
#pragma unroll
    for (int e = 0; e < 4; ++e) {
      r[e]     = f2bf(a0[e]);
      r[4 + e] = f2bf(a1[e]);
    }
    *reinterpret_cast<ushort8*>(xb + t * 8) = r;
  }
}

// ---- async global -> LDS, 16 B per lane ----
__device__ __forceinline__ void gld16(const void* g, void* l) {
  __builtin_amdgcn_global_load_lds(
      (const __attribute__((address_space(1))) unsigned int*)(uintptr_t)g,
      (__attribute__((address_space(3))) unsigned int*)(unsigned int)(uintptr_t)l,
      16, 0, 0);
}

#define BAR() do { asm volatile("" ::: "memory"); __builtin_amdgcn_s_barrier(); \
                   asm volatile("" ::: "memory"); } while (0)

// ---- kernel 3: 128x256 tile, BK=64, 8 waves (64x64 each), 4-phase iteration. ----
// Grid 2752 blocks -> 10.75/11 rounds (97.7% tail eff vs 89.6% at 256^2).
// Phase = {STAGE one kh of A+B (3 gld); RD next phase's frags (4A+4B, ping-pong);
//          vmcnt(6); BAR; MFMA 16 from current set}.
// Queue sim (3 loads/phase, FIFO): in-flight 6 -> 9 -> drain to 6 each phase;
//   P1-wait drains 1_kh0 (RD P2-top)   P2-wait drains 1_kh1 (RD P3-top)
//   P3-wait drains 0_kh0' (RD P4-top)  P4-wait drains 0_kh1' (RD next-P1-top)
// -> every RD is >=2 barriers after its publish; drain age = 3 phases.
// WAR: stage(region) is exactly 1 barrier after region's last phase-top read:
//   P1 stages 0_kh0' <- read prev-P4-top; P2: 0_kh1' <- P1-top; P3: 1_kh0' <- P2-top;
//   P4: 1_kh1' <- P3-top.  Prologue (12 loads + vmcnt(6)) == steady P1-entry state.
// LDS 96 KB: buf b at b*24576 (ushorts): A[2kh][128][32] then B[2kh][256][32];
// swizzle chunk^=((row>>1)&3); linear gld dest + inverse-swizzled global source.
__global__ __launch_bounds__(512, 2) void gemm_bt(const unsigned short* __restrict__ A,
                                                  const unsigned short* __restrict__ B,
                                                  float* __restrict__ C) {
  __shared__ __align__(16) unsigned short lds[49152];  // 96 KB

  const int NT  = OUT_F / BN;              // 43
  const int nwg = (M_ROWS / BM) * NT;      // 2752, %8==0
  const int cpx = nwg >> 3;
  const int bid = blockIdx.x;
  const int swz = (bid & 7) * cpx + (bid >> 3);
  const int mt  = swz / NT;
  const int nt  = swz - mt * NT;

  const int tid  = threadIdx.x;
  const int lane = tid & 63;
  const int wid  = tid >> 6;      // 8 waves: 2 (M) x 4 (N), each 64x64
  const int wr   = wid >> 2;      // 0..1 -> 64 rows
  const int wc   = wid & 3;       // 0..3 -> 64 cols

  // ---- staging: thread t -> row t>>2 (128-row sweep), phys chunk t&3;
  //      swizzled source chunk = (t&3) ^ ((row>>1)&3); 128-row sweep offsets
  //      don't perturb (row>>1)&3 (128s>>1 = 64s, &3 == 0). ----
  const int r_st = tid >> 2;
  const int lc   = (tid & 3) ^ ((tid >> 3) & 3);
  const unsigned short* gA = A + (size_t)(mt * BM + r_st) * IN_F + lc * 8;
  const unsigned short* gB = B + (size_t)(nt * BN + r_st) * IN_F + lc * 8;
  unsigned short* ldsw = lds + tid * 8;

  // region bases (ushorts): A: b*24576 + h*4096 ; B: b*24576 + 8192 + h*8192
#define STAGE_A(b, h, kk) do {                                              \
    gld16(gA + (kk) + (h) * 32, ldsw + (b) * 24576 + (h) * 4096);           \
  } while (0)
#define STAGE_B(b, h, kk) do {                                              \
    unsigned short* d_ = ldsw + (b) * 24576 + 8192 + (h) * 8192;            \
    const unsigned short* s_ = gB + (kk) + (h) * 32;                        \
    gld16(s_, d_); gld16(s_ + (size_t)128 * IN_F, d_ + 4096);               \
  } while (0)

  // ---- fragment reads: chunk = kq ^ ((fr>>1)&3) ----
  const int fr   = lane & 15;
  const int kq   = lane >> 4;
  const int coff = (kq ^ ((fr >> 1) & 3)) * 8;

  bf16x8 aS0[4], aS1[4], bS0[4], bS1[4];
#define RD_A(dst, b, h) do {                                                \
    const unsigned short* p_ = lds + (b) * 24576 + (h) * 4096 + coff;       \
    _Pragma("unroll") for (int mm = 0; mm < 4; ++mm)                        \
      dst[mm] = *reinterpret_cast<const bf16x8*>(                           \
          p_ + (size_t)(wr * 64 + mm * 16 + fr) * 32);                      \
  } while (0)
#define RD_B(dst, b, h) do {                                                \
    const unsigned short* p_ = lds + (b) * 24576 + 8192 + (h) * 8192 + coff; \
    _Pragma("unroll") for (int nn = 0; nn < 4; ++nn)                        \
      dst[nn] = *reinterpret_cast<const bf16x8*>(                           \
          p_ + (size_t)(wc * 64 + nn * 16 + fr) * 32);                      \
  } while (0)

  f32x4 acc[4][4] = {};
#define MFMA16(aset, bset) do {                                             \
    __builtin_amdgcn_s_setprio(1);                                          \
    _Pragma("unroll") for (int mm = 0; mm < 4; ++mm)                        \
      _Pragma("unroll") for (int nn = 0; nn < 4; ++nn)                      \
        acc[mm][nn] = __builtin_amdgcn_mfma_f32_16x16x32_bf16(              \
            aset[mm], bset[nn], acc[mm][nn], 0, 0, 0);                      \
    __builtin_amdgcn_s_setprio(0);                                          \
  } while (0)

#define VWAIT6() asm volatile("s_waitcnt vmcnt(6)" ::: "memory")

  // ---- prologue: 12 loads (Ta full, Tb full); vmcnt(6) -> Ta resident;
  //      in-flight = [1_kh0, 1_kh1] = steady P1-entry state ----
  STAGE_A(0, 0, 0);  STAGE_B(0, 0, 0);
  STAGE_A(0, 1, 0);  STAGE_B(0, 1, 0);
  STAGE_A(1, 0, BK); STAGE_B(1, 0, BK);
  STAGE_A(1, 1, BK); STAGE_B(1, 1, BK);
  VWAIT6();
  BAR();
  RD_A(aS0, 0, 0); RD_B(bS0, 0, 0);   // frags for MFMA(P1)

  for (int it = 0; it < NTILE_K / 2; ++it) {
    const int kt2 = ((2 * it + 2) & (NTILE_K - 1)) * BK;   // next Ta
    const int kt3 = ((2 * it + 3) & (NTILE_K - 1)) * BK;   // next Tb

    // P1: stage next-0 kh0 ; RD->P2 (Ta kh1) ; MFMA Ta kh0
    STAGE_A(0, 0, kt2); STAGE_B(0, 0, kt2);
    RD_A(aS1, 0, 1); RD_B(bS1, 0, 1);
    VWAIT6();
    BAR(); MFMA16(aS0, bS0);
    // P2: stage next-0 kh1 ; RD->P3 (Tb kh0) ; MFMA Ta kh1
    STAGE_A(0, 1, kt2); STAGE_B(0, 1, kt2);
    RD_A(aS0, 1, 0); RD_B(bS0, 1, 0);
    VWAIT6();
    BAR(); MFMA16(aS1, bS1);
    // P3: stage next-1 kh0 ; RD->P4 (Tb kh1) ; MFMA Tb kh0
    STAGE_A(1, 0, kt3); STAGE_B(1, 0, kt3);
    RD_A(aS1, 1, 1); RD_B(bS1, 1, 1);
    VWAIT6();
    BAR(); MFMA16(aS0, bS0);
    // P4: stage next-1 kh1 ; RD->next-P1 (next-Ta kh0) ; MFMA Tb kh1
    STAGE_A(1, 1, kt3); STAGE_B(1, 1, kt3);
    RD_A(aS0, 0, 0); RD_B(bS0, 0, 0);
    VWAIT6();
    BAR(); MFMA16(aS1, bS1);
  }

  // ---- epilogue: acc[m][n]: row = mt*128 + wr*64 + m*16 + (lane>>4)*4 + r,
  //      col = nt*256 + wc*64 + n*16 + fr ----
  const int col  = nt * BN + wc * 64 + fr;
  const int row0 = mt * BM + wr * 64 + (lane >> 4) * 4;
#pragma unroll
  for (int m = 0; m < 4; ++m) {
#pragma unroll
    for (int n = 0; n < 4; ++n) {
      float* cp = C + (size_t)(row0 + m * 16) * OUT_F + (col + n * 16);
#pragma unroll
      for (int r = 0; r < 4; ++r) cp[(size_t)r * OUT_F] = acc[m][n][r];
    }
  }
}

extern "C" void kernel_launch(void* const* d_in, const int* in_sizes, int n_in,
                              void* d_out, int out_size, void* d_ws, size_t ws_size,
                              hipStream_t stream) {
  const float* x = (const float*)d_in[0];
  const int*   w = (const int*)d_in[1];
  const float* s = (const float*)d_in[2];
  float*     out = (float*)d_out;

  unsigned short* wb = (unsigned short*)d_ws;             // bf16 W  [OUT_F][IN_F]
  unsigned short* xb = wb + (size_t)OUT_F * IN_F;         // bf16 x  [M_ROWS][IN_F]

  dequant_q40<<<dim3(2048), dim3(256), 0, stream>>>(w, s, wb);
  cvt_x<<<dim3(2048), dim3(256), 0, stream>>>(x, xb);
  gemm_bt<<<dim3((M_ROWS / BM) * (OUT_F / BN)), dim3(512), 0, stream>>>(xb, wb, out);
}